// Round 1
// baseline (105.202 us; speedup 1.0000x reference)
//
#include <hip/hip_runtime.h>

// ACT-R activation recurrence.
// act_i = log(sum_{j<i} max((t_i - t_j)*H, 1)^(-decay_j)),
// decay_j = w0 + w1 * exp(act_j) = w0 + w1 * s_j  where s_j is the raw sum.
// s_0 = 0 (m[0] = -inf) falls out naturally from acc init = 0.
// out[i-1, b] = sigmoid((act_i - TAU)/S), i = 1..L-1.

constexpr int   L        = 1024;
constexpr int   B        = 256;
constexpr int   T        = 64;     // triangle tile (rows per sequential block)
constexpr int   NTHREADS = 512;    // 8 waves per workgroup, 1 workgroup per batch elem

constexpr float H_CONST  = 86400.0f * 0.025f;        // 2160
constexpr float TAU_C    = -0.704205679427144f;
constexpr float S_C      = 0.254893976981164f;
constexpr float LN2      = 0.69314718055994530942f;
constexpr float LOG2E    = 1.4426950408889634074f;

__device__ __forceinline__ float fast_log2(float x) { return __builtin_amdgcn_logf(x); }
__device__ __forceinline__ float fast_exp2(float x) { return __builtin_amdgcn_exp2f(x); }
__device__ __forceinline__ float readlane_f(float v, int lane) {
    return __uint_as_float(__builtin_amdgcn_readlane(__float_as_uint(v), lane));
}

__global__ __launch_bounds__(NTHREADS, 2)
void actr_kernel(const float* __restrict__ sp, const float* __restrict__ w,
                 float* __restrict__ out)
{
    __shared__ float tH[L];      // t_i * H
    __shared__ float acc[L];     // running partial sum per row (cols processed so far)
    __shared__ float negdec[L];  // -decay_j

    const int b   = blockIdx.x;
    const int tid = threadIdx.x;
    const float w0 = w[0];
    const float w1 = w[1];

    // Load this batch element's timestamps, pre-multiplied by H.
    for (int i = tid; i < L; i += NTHREADS) {
        tH[i]  = sp[i * B + b] * H_CONST;
        acc[i] = 0.0f;
    }
    __syncthreads();

    for (int k = 0; k < L / T; ++k) {
        const int I0 = k * T;

        if (k > 0) {
            // Panel update: apply columns of block k-1 (decays just computed)
            // to every remaining row i >= I0. Each thread owns up to 2 rows ->
            // private accumulators, no reductions. tH[j]/negdec[j] reads are
            // wave-uniform (broadcast, conflict-free).
            const int base = I0 - T;
            for (int i0 = I0 + tid; i0 < L; i0 += 2 * NTHREADS) {
                const int i1 = i0 + NTHREADS;
                const bool has1 = (i1 < L);
                float a0 = acc[i0];
                float a1 = has1 ? acc[i1] : 0.0f;
                const float t0 = tH[i0];
                const float t1 = has1 ? tH[i1] : t0;
                #pragma unroll 8
                for (int j = 0; j < T; ++j) {
                    const float tj = tH[base + j];
                    const float nd = negdec[base + j];
                    const float lg0 = fast_log2(fmaxf(t0 - tj, 1.0f));
                    const float lg1 = fast_log2(fmaxf(t1 - tj, 1.0f));
                    a0 += fast_exp2(nd * lg0);
                    a1 += fast_exp2(nd * lg1);
                }
                acc[i0] = a0;
                if (has1) acc[i1] = a1;
            }
        }
        __syncthreads();

        // In-block triangle: wave 0, column-wise. Lane l owns row r = I0 + l.
        // Step jl: broadcast s_{I0+jl} from lane jl (its accumulator is complete),
        // all later lanes fold column jl into their private accumulator.
        if (tid < 64) {
            const int l = tid;
            const int r = I0 + l;
            float my_acc = acc[r];
            const float my_tH = tH[r];
            float my_s  = 0.0f;
            float my_nd = 0.0f;
            #pragma unroll
            for (int jl = 0; jl < T; ++jl) {
                const float s  = readlane_f(my_acc, jl);   // uniform lane -> v_readlane
                const float tj = readlane_f(my_tH, jl);
                const float nd = -(w0 + w1 * s);           // -decay_{I0+jl}
                const float lg = fast_log2(fmaxf(my_tH - tj, 1.0f));
                const float term = fast_exp2(nd * lg);
                if (l > jl) my_acc += term;
                if (l == jl) { my_s = s; my_nd = nd; }
            }
            negdec[r] = my_nd;
            if (r > 0) {
                const float act = fast_log2(my_s) * LN2;   // natural log of sum
                const float z = (TAU_C - act) / S_C;       // out = 1/(1+e^z)
                const float e = fast_exp2(z * LOG2E);
                out[(r - 1) * B + b] = 1.0f / (1.0f + e);
            }
        }
        __syncthreads();
    }
}

extern "C" void kernel_launch(void* const* d_in, const int* in_sizes, int n_in,
                              void* d_out, int out_size, void* d_ws, size_t ws_size,
                              hipStream_t stream) {
    const float* sp = (const float*)d_in[0];
    const float* w  = (const float*)d_in[1];
    float* out      = (float*)d_out;
    actr_kernel<<<dim3(B), dim3(NTHREADS), 0, stream>>>(sp, w, out);
}

// Round 2
// 86.107 us; speedup vs baseline: 1.2218x; 1.2218x over previous
//
#include <hip/hip_runtime.h>

// ACT-R activation recurrence, wave-specialized.
// s_i = sum_{j<i} max((t_i-t_j)*H,1)^(-decay_j),  decay_j = w0 + w1*s_j  (s_0=0)
// out[i-1,b] = sigmoid((ln(s_i) - TAU)/S), i=1..L-1.
//
// Blocked lower-triangular schedule, T=64 rows per block, 16 phases:
//   wave 0  (critical): apply col-block k-1 to its 64 rows, then run the
//                       64-step serial triangle of block k (readlane broadcast,
//                       logs + exp2(-w0*lg) hoisted off the dependence chain).
//   waves 1-15 (bulk):  apply col-block k-1 to all rows >= I0+T (1 row/thread).
// One __syncthreads per phase; bulk work hides under the serial chain.

constexpr int   L  = 1024;
constexpr int   B  = 256;
constexpr int   T  = 64;
constexpr int   NT = 1024;   // 16 waves

constexpr float H_CONST = 86400.0f * 0.025f;   // 2160
constexpr float TAU_C   = -0.704205679427144f;
constexpr float S_C     = 0.254893976981164f;
constexpr float LN2     = 0.69314718055994530942f;
constexpr float LOG2E   = 1.4426950408889634074f;

__device__ __forceinline__ float flog2(float x) { return __builtin_amdgcn_logf(x); }
__device__ __forceinline__ float fexp2(float x) { return __builtin_amdgcn_exp2f(x); }
__device__ __forceinline__ float rdlane(float v, int l) {
    return __uint_as_float(__builtin_amdgcn_readlane(__float_as_uint(v), l));
}

__global__ __launch_bounds__(NT)
void actr_kernel(const float* __restrict__ sp, const float* __restrict__ w,
                 float* __restrict__ out)
{
    __shared__ float  tH[L];    // t_i * H
    __shared__ float  acc[L];   // partial sums for rows not yet finalized
    __shared__ float2 col[L];   // finalized columns: {t_j*H, -decay_j}

    const int b   = blockIdx.x;
    const int tid = threadIdx.x;
    const float w0 = w[0];
    const float w1 = w[1];

    for (int i = tid; i < L; i += NT) {
        tH[i]  = sp[i * B + b] * H_CONST;
        acc[i] = 0.0f;
    }
    __syncthreads();

    for (int k = 0; k < L / T; ++k) {
        const int I0 = k * T;

        if (tid < 64) {
            // ---- critical wave: finish block k's rows, then triangle ----
            const int l = tid;
            const int r = I0 + l;
            const float my_t = tH[r];
            float a = acc[r];

            if (k > 0) {
                const int base = I0 - T;
                #pragma unroll
                for (int j = 0; j < T; ++j) {
                    const float2 c = col[base + j];   // broadcast read
                    a += fexp2(c.y * flog2(fmaxf(my_t - c.x, 1.0f)));
                }
            }

            // off-chain precompute for the triangle:
            //   lg_j  = log2(max(t_r - t_{I0+j}, 1))
            //   p_j   = exp2(-w0*lg_j) masked to 0 for l <= j
            //   q_j   = -w1*lg_j
            float pv[T];
            float qv[T];
            #pragma unroll
            for (int j = 0; j < T; ++j) {
                const float lg = flog2(fmaxf(my_t - rdlane(my_t, j), 1.0f));
                pv[j] = (l > j) ? fexp2(-w0 * lg) : 0.0f;
                qv[j] = -w1 * lg;
            }

            __builtin_amdgcn_s_setprio(1);
            float my_s = 0.0f;
            #pragma unroll
            for (int j = 0; j < T; ++j) {
                const float s = rdlane(a, j);          // chain: add -> readlane
                if (l == j) my_s = s;
                a = fmaf(pv[j], fexp2(qv[j] * s), a);  // -> mul -> exp2 -> fma
            }
            __builtin_amdgcn_s_setprio(0);

            col[r] = make_float2(my_t, -(w0 + w1 * my_s));
            if (r > 0) {
                const float act = flog2(my_s) * LN2;             // ln(s)
                const float e   = fexp2((TAU_C - act) * (LOG2E / S_C));
                out[(r - 1) * B + b] = 1.0f / (1.0f + e);
            }
        } else if (k > 0) {
            // ---- bulk waves: apply col-block k-1 to rows >= I0+T ----
            const int r = I0 + T + (tid - 64);
            if (r < L) {
                const int base = I0 - T;
                float a = acc[r];
                const float my_t = tH[r];
                #pragma unroll 16
                for (int j = 0; j < T; ++j) {
                    const float2 c = col[base + j];   // broadcast read
                    a += fexp2(c.y * flog2(fmaxf(my_t - c.x, 1.0f)));
                }
                acc[r] = a;
            }
        }
        __syncthreads();
    }
}

extern "C" void kernel_launch(void* const* d_in, const int* in_sizes, int n_in,
                              void* d_out, int out_size, void* d_ws, size_t ws_size,
                              hipStream_t stream) {
    const float* sp = (const float*)d_in[0];
    const float* w  = (const float*)d_in[1];
    float* out      = (float*)d_out;
    actr_kernel<<<dim3(B), dim3(NT), 0, stream>>>(sp, w, out);
}

// Round 3
// 58.534 us; speedup vs baseline: 1.7973x; 1.4710x over previous
//
#include <hip/hip_runtime.h>

// ACT-R activation recurrence, 3-role pipelined.
// s_i = sum_{j<i} max((t_i-t_j)*H,1)^(-decay_j),  decay_j = w0 + w1*s_j  (s_0=0)
// out[i-1,b] = sigmoid((ln(s_i)-TAU)/S), i=1..L-1.
//
// Per phase k (block of T=64 rows):
//  part 1 (all 1024 thr): STRIP  — apply cols[k-1] to block-k rows
//                         (16 thr/row, 4 cols each, shfl_xor reduce -> stripsum)
//  barrier
//  part 2: wave 0: TRIANGLE — pure 64-step serial chain
//                  (rdlane -> mul -> exp2 -> fma), (p,q) preloaded from LDS.
//                  Lane l's acc never changes after step l => my_s = final a.
//          waves 1..15: PANEL — apply cols[k-1] to rows >= I0+T (1 row/thread),
//                  and precompute ptq[(k+1)&1] for the next triangle
//                  (timestamp-only, independent of acc).
//  barrier
// Triangle is the only serial part left: ~64*20cyc * 16 phases ~ 13us target.

constexpr int   L  = 1024;
constexpr int   B  = 256;
constexpr int   T  = 64;
constexpr int   NT = 1024;   // 16 waves

constexpr float H_CONST = 86400.0f * 0.025f;   // 2160
constexpr float TAU_C   = -0.704205679427144f;
constexpr float S_C     = 0.254893976981164f;
constexpr float LN2     = 0.69314718055994530942f;
constexpr float LOG2E   = 1.4426950408889634074f;

__device__ __forceinline__ float flog2(float x) { return __builtin_amdgcn_logf(x); }
__device__ __forceinline__ float fexp2(float x) { return __builtin_amdgcn_exp2f(x); }
__device__ __forceinline__ float rdlane(float v, int l) {
    return __uint_as_float(__builtin_amdgcn_readlane(__float_as_uint(v), l));
}

__global__ __launch_bounds__(NT)
void actr_kernel(const float* __restrict__ sp, const float* __restrict__ w,
                 float* __restrict__ out)
{
    __shared__ float  tH[L];        // t_i * H
    __shared__ float  acc[L];       // partial sums (cols < current block)
    __shared__ float2 col[L];       // finalized columns {t_j*H, -decay_j}
    __shared__ float2 ptq[2][T*T];  // [j*T+l] = {p_masked, q} for the triangle
    __shared__ float  stripsum[T];  // strip partial for block-k rows

    const int b   = blockIdx.x;
    const int tid = threadIdx.x;
    const float w0 = w[0];
    const float w1 = w[1];

    for (int i = tid; i < L; i += NT) {
        tH[i]  = sp[i * B + b] * H_CONST;
        acc[i] = 0.0f;
    }
    if (tid < T) stripsum[tid] = 0.0f;
    __syncthreads();

    // prologue: ptq[0] for block 0
    for (int f = tid; f < T * T; f += NT) {
        const int j = f >> 6, l = f & 63;
        const float lg = flog2(fmaxf(tH[l] - tH[j], 1.0f));
        ptq[0][f] = make_float2((l > j) ? fexp2(-w0 * lg) : 0.0f, -w1 * lg);
    }
    __syncthreads();

    for (int k = 0; k < L / T; ++k) {
        const int I0 = k * T;

        // ---- part 1: strip (all threads; 16 threads per block-k row) ----
        if (k > 0) {
            const int rl   = tid >> 4;          // 0..63 local row
            const int c    = tid & 15;
            const int base = I0 - T;
            const float my_t = tH[I0 + rl];
            float p = 0.0f;
            #pragma unroll
            for (int u = 0; u < 4; ++u) {
                const float2 cj = col[base + c + 16 * u];
                p += fexp2(cj.y * flog2(fmaxf(my_t - cj.x, 1.0f)));
            }
            p += __shfl_xor(p, 1);
            p += __shfl_xor(p, 2);
            p += __shfl_xor(p, 4);
            p += __shfl_xor(p, 8);
            if (c == 0) stripsum[rl] = p;
        }
        __syncthreads();

        // ---- part 2 ----
        if (tid < 64) {
            // critical wave: pure serial triangle
            const int l = tid;
            const int r = I0 + l;
            const float2* __restrict__ pq = ptq[k & 1];
            float a = acc[r] + stripsum[l];     // stripsum = 0 at k = 0
            __builtin_amdgcn_s_setprio(1);
            #pragma unroll
            for (int j = 0; j < T; ++j) {
                const float2 cpq = pq[j * T + l];   // off-chain LDS load
                const float s = rdlane(a, j);       // chain: fma -> rdlane
                a = fmaf(cpq.x, fexp2(cpq.y * s), a); // -> mul -> exp2 -> fma
            }
            __builtin_amdgcn_s_setprio(0);
            const float my_s = a;               // lane l frozen after step l
            col[r] = make_float2(tH[r], -(w0 + w1 * my_s));
            if (r > 0) {
                const float act = flog2(my_s) * LN2;
                const float e   = fexp2((TAU_C - act) * (LOG2E / S_C));
                out[(r - 1) * B + b] = 1.0f / (1.0f + e);
            }
        } else {
            // bulk: panel for rows >= I0+T
            if (k > 0) {
                const int r = I0 + T + (tid - 64);
                if (r < L) {
                    const int base = I0 - T;
                    float a = acc[r];
                    const float my_t = tH[r];
                    #pragma unroll 16
                    for (int j = 0; j < T; ++j) {
                        const float2 cj = col[base + j];    // broadcast read
                        a += fexp2(cj.y * flog2(fmaxf(my_t - cj.x, 1.0f)));
                    }
                    acc[r] = a;
                }
            }
            // precompute next triangle's (p,q) — timestamps only
            if (k < L / T - 1) {
                const int I1 = I0 + T;
                for (int f = tid - 64; f < T * T; f += NT - 64) {
                    const int j = f >> 6, l2 = f & 63;
                    const float lg = flog2(fmaxf(tH[I1 + l2] - tH[I1 + j], 1.0f));
                    ptq[(k + 1) & 1][f] =
                        make_float2((l2 > j) ? fexp2(-w0 * lg) : 0.0f, -w1 * lg);
                }
            }
        }
        __syncthreads();
    }
}

extern "C" void kernel_launch(void* const* d_in, const int* in_sizes, int n_in,
                              void* d_out, int out_size, void* d_ws, size_t ws_size,
                              hipStream_t stream) {
    const float* sp = (const float*)d_in[0];
    const float* w  = (const float*)d_in[1];
    float* out      = (float*)d_out;
    actr_kernel<<<dim3(B), dim3(NT), 0, stream>>>(sp, w, out);
}